// Round 8
// baseline (89.132 us; speedup 1.0000x reference)
//
#include <hip/hip_runtime.h>
#include <cstdint>
#include <cstddef>

// Problem constants (fixed by the reference)
constexpr int Bc = 4, Tc = 4096, Ec = 1024, Hc = 16, Dc = 64, CHc = 64;
constexpr int NSEG = 16;              // pass3 segments (4 chunks serial, S in regs)
constexpr int SEGT = Tc / NSEG;       // 256 tokens
constexpr int NCHUNK = SEGT / CHc;    // 4
constexpr int NHALF = 32;             // pass1 half-segments (2 chunks each, pure sum)

typedef __attribute__((ext_vector_type(8))) short short8;  // 8 bf16 MFMA A/B frag
typedef __attribute__((ext_vector_type(4))) float f32x4;   // MFMA C/D frag

// XOR-swizzled LDS tile addressing: [64][64] bf16, 128B rows, no pad (T2).
__device__ __forceinline__ unsigned short* sws(unsigned short* b, int row, int colbyte) {
  return (unsigned short*)((char*)b + (row << 7) + (colbyte ^ ((row & 7) << 4)));
}

__device__ __forceinline__ unsigned short f2bf(float f) {  // RNE (prep only)
  union { float f; unsigned int u; } v; v.f = f;
  return (unsigned short)((v.u + 0x7FFFu + ((v.u >> 16) & 1u)) >> 16);
}
// round-half-up pack of 2 fp32 -> u32(2xbf16) via v_perm_b32: 3 VALU ops.
__device__ __forceinline__ unsigned int pk2(float lo, float hi) {
  union { float f; unsigned int u; } a, b; a.f = lo; b.f = hi;
  return __builtin_amdgcn_perm(b.u + 0x8000u, a.u + 0x8000u, 0x07060302u);
}
__device__ __forceinline__ float bf2f(unsigned int u16) {  // low 16 bits = bf16
  union { unsigned int u; float f; } v; v.u = u16 << 16;
  return v.f;
}
__device__ __forceinline__ float phi_elu1(float x) {   // elu(x)+1
  return x > 0.f ? x + 1.f : __expf(x);
}
__device__ __forceinline__ short8 ld8(const unsigned short* p) {
  return *reinterpret_cast<const short8*>(p);
}
__device__ __forceinline__ short8 pk8(float4 a, float4 b) {
  union { unsigned int u[4]; short8 s; } r;
  r.u[0] = pk2(a.x, a.y); r.u[1] = pk2(a.z, a.w);
  r.u[2] = pk2(b.x, b.y); r.u[3] = pk2(b.z, b.w);
  return r.s;
}
__device__ __forceinline__ void st4(unsigned short* p, float v0, float v1, float v2, float v3) {
  uint2 t; t.x = pk2(v0, v1); t.y = pk2(v2, v3);
  *reinterpret_cast<uint2*>(p) = t;
}

#define MFMA(a, b, c) __builtin_amdgcn_mfma_f32_16x16x32_bf16((a), (b), (c), 0, 0, 0)

// ---------------- prep: wqT[e][d], wkT[e][d], wvoT[d][f] (Wvo = Wv@Wo) -> bf16 ----------------
__global__ __launch_bounds__(256) void prep_weights(
    const float* __restrict__ Wq, const float* __restrict__ Wk,
    const float* __restrict__ Wv, const float* __restrict__ Wo,
    unsigned short* __restrict__ wbuf) {
  __shared__ float s_wvT[4096];  // [g][f] = Wv[f][g]
  __shared__ float s_wo[4096];   // [g][d] = Wo[g][d]
  const int tid = threadIdx.x;
  const int i = blockIdx.x * 256 + tid;          // 0..4095
  for (int j = tid; j < 4096; j += 256) {
    s_wvT[(j & 63) * 64 + (j >> 6)] = Wv[j];
    s_wo[j] = Wo[j];
  }
  __syncthreads();
  const int r = i >> 6, c = i & 63;
  wbuf[c * 64 + r] = f2bf(Wq[i]);                // wqT[e][d] = Wq[d][e]
  wbuf[4096 + c * 64 + r] = f2bf(Wk[i]);         // wkT
  float acc = 0.f;                               // wvoT[d][f] = (Wv@Wo)[f][d];  d=r, f=c
  for (int g = 0; g < 64; ++g)
    acc += s_wvT[g * 64 + c] * s_wo[g * 64 + r];
  wbuf[8192 + i] = f2bf(acc);
}

// ---------------- pass1: per-HALF-SEGMENT KV' = sum_t phi(k)^T v' -> bf16 S^T[d][e] ----------------
// Pure sum (no order dependency) -> grid (64,32) = 2048 blocks, 2 chunks serial.
__global__ __launch_bounds__(256, 3) void pass1_kvhalf(
    const float* __restrict__ x, const unsigned short* __restrict__ wbuf,
    unsigned short* __restrict__ kvh) {
  __shared__ unsigned short s_kT[4096];   // phi(k)^T [e][t]  (swizzled)
  __shared__ unsigned short s_vT[4096];   // v'^T [d][t]      (swizzled)
  const int tid = threadIdx.x, w = tid >> 6, lane = tid & 63, lr = lane & 15, lq = lane >> 4;
  const int bh = blockIdx.x, hs = blockIdx.y, b = bh >> 4, h = bh & 15;
  const float* xbase = x + ((size_t)b * Tc + (size_t)hs * 2 * CHc) * Ec + h * Dc;
  const unsigned short* wkT = wbuf + 4096;
  const unsigned short* wvoT = wbuf + 8192;
  const f32x4 Z = {0.f, 0.f, 0.f, 0.f};

  short8 bwk[4][2], bwv[4][2];   // B-side weight frags (rows e / d = c*16+lr)
#pragma unroll
  for (int c = 0; c < 4; ++c)
#pragma unroll
    for (int kk = 0; kk < 2; ++kk) {
      bwk[c][kk] = ld8(wkT + (c * 16 + lr) * 64 + kk * 32 + lq * 8);
      bwv[c][kk] = ld8(wvoT + (c * 16 + lr) * 64 + kk * 32 + lq * 8);
    }

  // preload chunk0 x: own row (w*16+lr), cols lq*8..+8 and 32+lq*8..+8
  const float* xr = xbase + (size_t)(w * 16 + lr) * Ec + lq * 8;
  float4 p0 = ((const float4*)xr)[0], p1 = ((const float4*)xr)[1];
  float4 p2 = ((const float4*)(xr + 32))[0], p3 = ((const float4*)(xr + 32))[1];

  f32x4 sacc[4] = {Z, Z, Z, Z};
#pragma unroll
  for (int ci = 0; ci < 2; ++ci) {
    short8 xa0 = pk8(p0, p1), xa1 = pk8(p2, p3);
    if (ci == 0) {
      const float* nr = xbase + (size_t)(CHc + w * 16 + lr) * Ec + lq * 8;
      p0 = ((const float4*)nr)[0]; p1 = ((const float4*)nr)[1];
      p2 = ((const float4*)(nr + 32))[0]; p3 = ((const float4*)(nr + 32))[1];
    }
    f32x4 ak[4] = {Z, Z, Z, Z}, av[4] = {Z, Z, Z, Z};
#pragma unroll
    for (int c = 0; c < 4; ++c) {
      ak[c] = MFMA(xa0, bwk[c][0], ak[c]); ak[c] = MFMA(xa1, bwk[c][1], ak[c]);  // kT[e][t]
      av[c] = MFMA(xa0, bwv[c][0], av[c]); av[c] = MFMA(xa1, bwv[c][1], av[c]);  // v'T[d][t]
    }
#pragma unroll
    for (int c = 0; c < 4; ++c) {
      st4(sws(s_kT, c * 16 + lr, w * 32 + lq * 8),
          phi_elu1(ak[c][0]), phi_elu1(ak[c][1]), phi_elu1(ak[c][2]), phi_elu1(ak[c][3]));
      st4(sws(s_vT, c * 16 + lr, w * 32 + lq * 8), av[c][0], av[c][1], av[c][2], av[c][3]);
    }
    __syncthreads();  // B1
    short8 akt0 = ld8(sws(s_kT, w * 16 + lr, lq * 16));
    short8 akt1 = ld8(sws(s_kT, w * 16 + lr, 64 + lq * 16));
#pragma unroll
    for (int c = 0; c < 4; ++c) {
      sacc[c] = MFMA(akt0, ld8(sws(s_vT, c * 16 + lr, lq * 16)), sacc[c]);
      sacc[c] = MFMA(akt1, ld8(sws(s_vT, c * 16 + lr, 64 + lq * 16)), sacc[c]);
    }
    __syncthreads();  // B2
  }
  // transposed bf16 store: S^T[d][e], 8B packed
  unsigned short* dst = kvh + ((size_t)bh * NHALF + hs) * 4096;
#pragma unroll
  for (int c = 0; c < 4; ++c) {
    uint2 t; t.x = pk2(sacc[c][0], sacc[c][1]); t.y = pk2(sacc[c][2], sacc[c][3]);
    *reinterpret_cast<uint2*>(dst + (c * 16 + lr) * 64 + w * 16 + lq * 4) = t;
  }
}

// ---------------- pass2: exclusive prefix over 32 half-KVs -> 16 segment prefixes (bf16) ----------------
__global__ __launch_bounds__(256) void pass2_prefix(const unsigned short* __restrict__ kvh,
                                                    unsigned short* __restrict__ spre) {
  const int bh = blockIdx.x, tile = blockIdx.y;
  const int e4 = tile * 1024 + threadIdx.x * 4;
  const unsigned short* src = kvh + (size_t)bh * NHALF * 4096 + e4;
  unsigned short* dst = spre + (size_t)bh * NSEG * 4096 + e4;
  uint2 vals[NHALF];
#pragma unroll
  for (int s = 0; s < NHALF; ++s) vals[s] = *(const uint2*)(src + (size_t)s * 4096);
  float a0 = 0.f, a1 = 0.f, a2 = 0.f, a3 = 0.f;
#pragma unroll
  for (int s = 0; s < NHALF; ++s) {
    if ((s & 1) == 0) {   // segment boundary: exclusive prefix (before adding this half)
      uint2 t; t.x = pk2(a0, a1); t.y = pk2(a2, a3);
      *reinterpret_cast<uint2*>(dst + (size_t)(s >> 1) * 4096) = t;
    }
    a0 += bf2f(vals[s].x & 0xFFFFu); a1 += bf2f(vals[s].x >> 16);
    a2 += bf2f(vals[s].y & 0xFFFFu); a3 += bf2f(vals[s].y >> 16);
  }
}

// ---------------- pass3: 512 threads / 8 waves; wave=(wr,wc) owns 2 output tiles ----------------
// x double-buffered (no restage race); 7x8KB=56KB LDS; target VGPR<=128 -> 2 blocks/CU.
__global__ __launch_bounds__(512, 2) void pass3_main(
    const float* __restrict__ x, const unsigned short* __restrict__ wbuf,
    const unsigned short* __restrict__ spre, float* __restrict__ out) {
  __shared__ unsigned short s_xb[2][4096];  // x chunk dbuf; cur half becomes attn in stage B
  __shared__ unsigned short s_q [4096];     // q [t][e]
  __shared__ unsigned short s_k [4096];     // k [t'][e]
  __shared__ unsigned short s_kT[4096];     // phi(k)^T [e][t]
  __shared__ unsigned short s_vT[4096];     // v'^T [d][t]
  __shared__ unsigned short s_Sb[4096];     // S^T [d][e] snapshot (pre-update)

  const int tid = threadIdx.x, w = tid >> 6, lane = tid & 63, lr = lane & 15, lq = lane >> 4;
  const int wr = w & 3, wc = w >> 2;        // row strip / col half
  const int sr8 = tid >> 3, sc8 = tid & 7;  // staging map: row sr8, 8 cols at sc8*8
  const int bh = blockIdx.x, sg = blockIdx.y, b = bh >> 4, h = bh & 15;
  const float* xbase = x + ((size_t)b * Tc + (size_t)sg * SEGT) * Ec + h * Dc;
  float* obase = out + ((size_t)b * Tc + (size_t)sg * SEGT) * Ec + h * Dc;
  const unsigned short* wqT = wbuf;
  const unsigned short* wkT = wbuf + 4096;
  const unsigned short* wvoT = wbuf + 8192;
  const unsigned short* SgT = spre + ((size_t)(bh * NSEG + sg)) * 4096;  // S^T[d][e] bf16
  const f32x4 Z = {0.f, 0.f, 0.f, 0.f};

  const int rA = wr * 16 + lr;              // A-side row (own strip)
  const int r0 = (2 * wc) * 16 + lr;        // B-side rows (wave's 2 col tiles)
  const int r1 = (2 * wc + 1) * 16 + lr;

  // running state S[e][d] rows e = wr strip, cols d = wave's 2 tiles; init = exclusive prefix
  f32x4 sacc[2];
  {
    uint2 u0 = *(const uint2*)(SgT + r0 * 64 + wr * 16 + lq * 4);
    uint2 u1 = *(const uint2*)(SgT + r1 * 64 + wr * 16 + lq * 4);
    sacc[0][0] = bf2f(u0.x & 0xFFFFu); sacc[0][1] = bf2f(u0.x >> 16);
    sacc[0][2] = bf2f(u0.y & 0xFFFFu); sacc[0][3] = bf2f(u0.y >> 16);
    sacc[1][0] = bf2f(u1.x & 0xFFFFu); sacc[1][1] = bf2f(u1.x >> 16);
    sacc[1][2] = bf2f(u1.y & 0xFFFFu); sacc[1][3] = bf2f(u1.y >> 16);
  }

  // weight fragments in registers (12 frags = 48 VGPR)
  short8 awq[2], awk[2], bwk[2][2], bwv[2][2];
#pragma unroll
  for (int kk = 0; kk < 2; ++kk) {
    awq[kk] = ld8(wqT + rA * 64 + kk * 32 + lq * 8);
    awk[kk] = ld8(wkT + rA * 64 + kk * 32 + lq * 8);
    bwk[0][kk] = ld8(wkT + r0 * 64 + kk * 32 + lq * 8);
    bwk[1][kk] = ld8(wkT + r1 * 64 + kk * 32 + lq * 8);
    bwv[0][kk] = ld8(wvoT + r0 * 64 + kk * 32 + lq * 8);
    bwv[1][kk] = ld8(wvoT + r1 * 64 + kk * 32 + lq * 8);
  }

  {  // stage chunk0 x -> buf0 (swizzled); thread: row sr8, cols sc8*8..+8
    const float4* xf = (const float4*)(xbase + (size_t)sr8 * Ec + sc8 * 8);
    *(short8*)sws(s_xb[0], sr8, sc8 * 16) = pk8(xf[0], xf[1]);
  }
  __syncthreads();

#pragma unroll
  for (int ci = 0; ci < NCHUNK; ++ci) {
    unsigned short* cur = s_xb[ci & 1];
    unsigned short* nxt = s_xb[(ci & 1) ^ 1];

    // ---- stage A: 4 projections (2 c-tiles each); transposed b64-packed stores ----
    short8 xb0[2], xb1[2], xw[2];
#pragma unroll
    for (int kk = 0; kk < 2; ++kk) {
      xb0[kk] = ld8(sws(cur, r0, kk * 64 + lq * 16));
      xb1[kk] = ld8(sws(cur, r1, kk * 64 + lq * 16));
      xw[kk]  = ld8(sws(cur, rA, kk * 64 + lq * 16));
    }
    st4(sws(s_Sb, r0, wr * 32 + lq * 8), sacc[0][0], sacc[0][1], sacc[0][2], sacc[0][3]);
    st4(sws(s_Sb, r1, wr * 32 + lq * 8), sacc[1][0], sacc[1][1], sacc[1][2], sacc[1][3]);

    f32x4 aqt[2] = {Z, Z}, akt[2] = {Z, Z}, ack[2] = {Z, Z}, acv[2] = {Z, Z};
    aqt[0] = MFMA(awq[0], xb0[0], aqt[0]); aqt[0] = MFMA(awq[1], xb0[1], aqt[0]);  // qT[e][t]
    aqt[1] = MFMA(awq[0], xb1[0], aqt[1]); aqt[1] = MFMA(awq[1], xb1[1], aqt[1]);
    akt[0] = MFMA(awk[0], xb0[0], akt[0]); akt[0] = MFMA(awk[1], xb0[1], akt[0]);  // kT[e][t']
    akt[1] = MFMA(awk[0], xb1[0], akt[1]); akt[1] = MFMA(awk[1], xb1[1], akt[1]);
    ack[0] = MFMA(xw[0], bwk[0][0], ack[0]); ack[0] = MFMA(xw[1], bwk[0][1], ack[0]);  // k[t][e]
    ack[1] = MFMA(xw[0], bwk[1][0], ack[1]); ack[1] = MFMA(xw[1], bwk[1][1], ack[1]);
    acv[0] = MFMA(xw[0], bwv[0][0], acv[0]); acv[0] = MFMA(xw[1], bwv[0][1], acv[0]);  // v'[t][d]
    acv[1] = MFMA(xw[0], bwv[1][0], acv[1]); acv[1] = MFMA(xw[1], bwv[1][1], acv[1]);

#pragma unroll
    for (int c2 = 0; c2 < 2; ++c2) {
      const int row = c2 ? r1 : r0, cb = wr * 32 + lq * 8;
      st4(sws(s_q, row, cb), phi_elu1(aqt[c2][0]), phi_elu1(aqt[c2][1]), phi_elu1(aqt[c2][2]), phi_elu1(aqt[c2][3]));
      st4(sws(s_k, row, cb), phi_elu1(akt[c2][0]), phi_elu1(akt[c2][1]), phi_elu1(akt[c2][2]), phi_elu1(akt[c2][3]));
      st4(sws(s_kT, row, cb), phi_elu1(ack[c2][0]), phi_elu1(ack[c2][1]), phi_elu1(ack[c2][2]), phi_elu1(ack[c2][3]));
      st4(sws(s_vT, row, cb), acv[c2][0], acv[c2][1], acv[c2][2], acv[c2][3]);
    }
    __syncthreads();  // B1

    // prefetch next chunk's x (latency hidden under stages B+C)
    float4 pf0, pf1;
    if (ci < NCHUNK - 1) {
      const float4* xf = (const float4*)(xbase + (size_t)((ci + 1) * CHc + sr8) * Ec + sc8 * 8);
      pf0 = xf[0]; pf1 = xf[1];
    }

    // ---- stage B: attnT = k q^T (masked); o_inter = q@S; S += kT@v' ----
    short8 aq[2], ak2[2], at[2];
#pragma unroll
    for (int kk = 0; kk < 2; ++kk) {
      aq[kk]  = ld8(sws(s_q, rA, kk * 64 + lq * 16));
      ak2[kk] = ld8(sws(s_k, rA, kk * 64 + lq * 16));
      at[kk]  = ld8(sws(s_kT, rA, kk * 64 + lq * 16));
    }
    f32x4 aat[2] = {Z, Z}, ao[2] = {Z, Z};
#pragma unroll
    for (int c2 = 0; c2 < 2; ++c2) {
      const int row = c2 ? r1 : r0;
      aat[c2]  = MFMA(ak2[0], ld8(sws(s_q, row, lq * 16)), aat[c2]);
      aat[c2]  = MFMA(ak2[1], ld8(sws(s_q, row, 64 + lq * 16)), aat[c2]);
      ao[c2]   = MFMA(aq[0], ld8(sws(s_Sb, row, lq * 16)), ao[c2]);
      ao[c2]   = MFMA(aq[1], ld8(sws(s_Sb, row, 64 + lq * 16)), ao[c2]);
      sacc[c2] = MFMA(at[0], ld8(sws(s_vT, row, lq * 16)), sacc[c2]);
      sacc[c2] = MFMA(at[1], ld8(sws(s_vT, row, 64 + lq * 16)), sacc[c2]);
    }
    // masked attnT (acc row t'=wr16+lq*4+j, col t=c*16+lr) -> store attn[t][t'] into cur
#pragma unroll
    for (int c2 = 0; c2 < 2; ++c2) {
      const int t = c2 ? r1 : r0, tp = wr * 16 + lq * 4;
      float m0 = (tp + 0 <= t) ? aat[c2][0] : 0.f;
      float m1 = (tp + 1 <= t) ? aat[c2][1] : 0.f;
      float m2 = (tp + 2 <= t) ? aat[c2][2] : 0.f;
      float m3 = (tp + 3 <= t) ? aat[c2][3] : 0.f;
      st4(sws(cur, t, tp * 2), m0, m1, m2, m3);
    }
    __syncthreads();  // B2

    // ---- stage C: o += attn@v'; out from fp32 acc; restage next x into nxt buf ----
    short8 aa[2];
    aa[0] = ld8(sws(cur, rA, lq * 16));
    aa[1] = ld8(sws(cur, rA, 64 + lq * 16));
#pragma unroll
    for (int c2 = 0; c2 < 2; ++c2) {
      const int row = c2 ? r1 : r0;
      ao[c2] = MFMA(aa[0], ld8(sws(s_vT, row, lq * 16)), ao[c2]);
      ao[c2] = MFMA(aa[1], ld8(sws(s_vT, row, 64 + lq * 16)), ao[c2]);
    }
    float* orow = obase + (size_t)(ci * CHc) * Ec;
#pragma unroll
    for (int c2 = 0; c2 < 2; ++c2) {
      const int col = c2 ? r1 : r0;
#pragma unroll
      for (int j = 0; j < 4; ++j)
        orow[(size_t)(wr * 16 + lq * 4 + j) * Ec + col] = ao[c2][j];
    }
    if (ci < NCHUNK - 1)
      *(short8*)sws(nxt, sr8, sc8 * 16) = pk8(pf0, pf1);
    __syncthreads();  // B3
  }
}

extern "C" void kernel_launch(void* const* d_in, const int* in_sizes, int n_in,
                              void* d_out, int out_size, void* d_ws, size_t ws_size,
                              hipStream_t stream) {
  const float* x  = (const float*)d_in[0];
  const float* Wq = (const float*)d_in[1];
  const float* Wk = (const float*)d_in[2];
  const float* Wv = (const float*)d_in[3];
  const float* Wo = (const float*)d_in[4];
  float* out = (float*)d_out;

  unsigned short* wbuf = (unsigned short*)d_ws;                     // 24 KB used (reserve 32 KB)
  unsigned short* kvh  = (unsigned short*)((char*)d_ws + 32768);    // 16 MB bf16 S^T per (bh,half)
  unsigned short* spre = (unsigned short*)((char*)d_ws + 32768 + (size_t)16 * 1024 * 1024);  // 8 MB bf16

  prep_weights<<<dim3(16), dim3(256), 0, stream>>>(Wq, Wk, Wv, Wo, wbuf);
  pass1_kvhalf<<<dim3(64, NHALF), dim3(256), 0, stream>>>(x, wbuf, kvh);
  pass2_prefix<<<dim3(64, 4), dim3(256), 0, stream>>>(kvh, spre);
  pass3_main<<<dim3(64, NSEG), dim3(512), 0, stream>>>(x, wbuf, spre, out);
}